// Round 16
// baseline (249.496 us; speedup 1.0000x reference)
//
#include <hip/hip_runtime.h>
#include <hip/hip_bf16.h>

#define B_ 2
#define N_ 2048
#define H_ 8
#define DH_ 128
#define D_ 1024
#define NO_ 3072
#define SCALE_ 0.08838834764831845f

typedef __bf16 bf16;
typedef __bf16 bf16x4 __attribute__((ext_vector_type(4)));
typedef __bf16 bf16x8 __attribute__((ext_vector_type(8)));
typedef float f32x4 __attribute__((ext_vector_type(4)));

__device__ inline f32x4 mfma16(bf16x8 a, bf16x8 b, f32x4 c) {
  return __builtin_amdgcn_mfma_f32_16x16x32_bf16(a, b, c, 0, 0, 0);
}

__device__ inline float elu1(float x) { return x > 0.f ? x + 1.f : __expf(x); }

// async global->LDS 16B: lds dest = wave-uniform base + lane*16
__device__ inline void gl_lds16(const bf16* g, bf16* l) {
  __builtin_amdgcn_global_load_lds(
      (const __attribute__((address_space(1))) unsigned int*)g,
      (__attribute__((address_space(3))) unsigned int*)l, 16, 0, 0);
}

// --- shared GEMM body: C[M][N] = A[M][K] @ B[N][K]^T; BK=64, XOR-swizzled
//     LDS (content swizzle on the per-lane GLOBAL source of global_load_lds;
//     reads use the same involution). ---
template <typename OT>
__device__ inline void gemm_body(const bf16* __restrict__ A, const bf16* __restrict__ B,
                                 OT* __restrict__ C, int Nn, int K, int m0, int n0,
                                 bf16* sA, bf16* sB, int t) {
  int w = t >> 6, lane = t & 63, quad = lane >> 4, l16 = lane & 15;
  int wr = (w & 1) * 64, wc = (w >> 1) * 64;
  f32x4 zf = {0.f, 0.f, 0.f, 0.f};
  f32x4 acc[4][4];
#pragma unroll
  for (int a = 0; a < 4; a++)
#pragma unroll
    for (int c = 0; c < 4; c++) acc[a][c] = zf;
  int r8 = lane >> 3, c8 = lane & 7;   // 8 rows x 8 16B-chunks per issue
  for (int k0 = 0; k0 < K; k0 += 64) {
    __syncthreads();
#pragma unroll
    for (int j = 0; j < 4; j++) {
      int prow = w * 32 + j * 8 + r8;
      int co = (c8 ^ (prow & 7)) * 8;
      gl_lds16(A + (size_t)(m0 + prow) * K + k0 + co, sA + (w * 32 + j * 8) * 64);
      gl_lds16(B + (size_t)(n0 + prow) * K + k0 + co, sB + (w * 32 + j * 8) * 64);
    }
    __syncthreads();
#pragma unroll
    for (int ks = 0; ks < 2; ks++) {
      bf16x8 af[4], bfr[4];
#pragma unroll
      for (int mt = 0; mt < 4; mt++) {
        int row = wr + mt * 16 + l16;
        af[mt] = *(const bf16x8*)(sA + row * 64 + ((ks * 32 + quad * 8) ^ ((row & 7) << 3)));
      }
#pragma unroll
      for (int nt = 0; nt < 4; nt++) {
        int row = wc + nt * 16 + l16;
        bfr[nt] = *(const bf16x8*)(sB + row * 64 + ((ks * 32 + quad * 8) ^ ((row & 7) << 3)));
      }
#pragma unroll
      for (int mt = 0; mt < 4; mt++)
#pragma unroll
        for (int nt = 0; nt < 4; nt++)
          acc[mt][nt] = mfma16(af[mt], bfr[nt], acc[mt][nt]);
    }
  }
#pragma unroll
  for (int mt = 0; mt < 4; mt++)
#pragma unroll
    for (int nt = 0; nt < 4; nt++) {
      int row = m0 + wr + mt * 16 + quad * 4;
      int col = n0 + wc + nt * 16 + l16;
      OT* cp = C + (size_t)row * Nn + col;
#pragma unroll
      for (int r = 0; r < 4; r++) cp[(size_t)r * Nn] = (OT)acc[mt][nt][r];
    }
}

// ------- front: rmsnorm (blocks 0..4095) | weight cvt (4096..8191) |
//         mkvT + out_kv/out_norm init (8192..8207) -------
__global__ __launch_bounds__(256) void k_front(const float* __restrict__ x,
                                               const float* __restrict__ gamma,
                                               bf16* __restrict__ xn,
                                               const float4* __restrict__ wa, bf16x4* __restrict__ oa, int na4,
                                               const float4* __restrict__ wb, bf16x4* __restrict__ ob, int nb4,
                                               const float* __restrict__ mem_kv,
                                               const float* __restrict__ mem_norm,
                                               bf16* __restrict__ mkvT,
                                               float* __restrict__ out_kv,
                                               float* __restrict__ out_norm) {
  int blk = blockIdx.x;
  int t = threadIdx.x;
  if (blk < B_ * N_) {
    // ---- RMSNorm row ----
    int row = blk;
    const float4* xr = (const float4*)(x + (size_t)row * D_);
    float4 xv = xr[t];
    float ss = xv.x*xv.x + xv.y*xv.y + xv.z*xv.z + xv.w*xv.w;
#pragma unroll
    for (int m = 1; m < 64; m <<= 1) ss += __shfl_xor(ss, m);
    __shared__ float sred[4];
    if ((t & 63) == 0) sred[t >> 6] = ss;
    __syncthreads();
    float tot = sred[0] + sred[1] + sred[2] + sred[3];
    float scale = 32.0f / fmaxf(sqrtf(tot), 1e-12f);
    float4 gv = ((const float4*)gamma)[t];
    bf16x4 ov;
    ov[0] = (bf16)(xv.x * scale * gv.x);
    ov[1] = (bf16)(xv.y * scale * gv.y);
    ov[2] = (bf16)(xv.z * scale * gv.z);
    ov[3] = (bf16)(xv.w * scale * gv.w);
    *(bf16x4*)(xn + (size_t)row * D_ + t * 4) = ov;
  } else if (blk < 2 * B_ * N_) {
    // ---- weight fp32->bf16 ----
    int i = (blk - B_ * N_) * 256 + t;
    if (i < na4) {
      float4 v = wa[i];
      bf16x4 o;
      o[0] = (bf16)v.x; o[1] = (bf16)v.y; o[2] = (bf16)v.z; o[3] = (bf16)v.w;
      oa[i] = o;
    } else {
      int j = i - na4;
      if (j < nb4) {
        float4 v = wb[j];
        bf16x4 o;
        o[0] = (bf16)v.x; o[1] = (bf16)v.y; o[2] = (bf16)v.z; o[3] = (bf16)v.w;
        ob[j] = o;
      }
    }
  } else {
    // ---- mkvT transpose + out_kv/out_norm init ----
    int bh = blk - 2 * B_ * N_;
    int v = t & 127, khalf = t >> 7;
    const float* src = mem_kv + (size_t)bh * DH_ * DH_;
    bf16* dst = mkvT + (size_t)bh * DH_ * DH_ + (size_t)v * DH_ + khalf * 64;
#pragma unroll
    for (int kk8 = 0; kk8 < 8; kk8++) {
      int k0 = khalf * 64 + kk8 * 8;
      bf16x8 o;
#pragma unroll
      for (int e = 0; e < 8; e++) o[e] = (bf16)src[(size_t)(k0 + e) * DH_ + v];
      *(bf16x8*)(dst + kk8 * 8) = o;
    }
    const float4* s4 = (const float4*)src;
    float4* d4 = (float4*)(out_kv + (size_t)bh * DH_ * DH_);
#pragma unroll
    for (int i = 0; i < 16; i++) d4[t + i * 256] = s4[t + i * 256];
    if (t < DH_) out_norm[(size_t)bh * DH_ + t] = mem_norm[(size_t)bh * DH_ + t];
  }
}

// --- qkv GEMM launcher (bijective XCD swizzle via gridDim) ---
__global__ __launch_bounds__(256) void k_gemm_qkv(const bf16* __restrict__ A,
                                                  const bf16* __restrict__ B,
                                                  bf16* __restrict__ C,
                                                  int Nn, int K) {
  __shared__ __align__(16) bf16 sA[128 * 64];
  __shared__ __align__(16) bf16 sB[128 * 64];
  int lin = blockIdx.y * gridDim.x + blockIdx.x;
  int cpx = (gridDim.x * gridDim.y) >> 3;
  int swz = (lin & 7) * cpx + (lin >> 3);
  int bx = swz % gridDim.x, by = swz / gridDim.x;
  gemm_body<bf16>(A, B, C, Nn, K, by * 128, bx * 128, sA, sB, threadIdx.x);
}

// --- prep2: 64 tokens x 1 head per block. RoPE(q,k) -> qr,kr (n-major);
//     kf,v -> kfT,vT (d-major via LDS transpose); qden/kden reductions. ---
__global__ __launch_bounds__(256) void k_prep2(const bf16* __restrict__ qkv,
                                               const float* __restrict__ mem_norm,
                                               bf16* __restrict__ qr, bf16* __restrict__ kr,
                                               bf16* __restrict__ vT, bf16* __restrict__ kfT,
                                               float* __restrict__ qden, float* __restrict__ kden) {
  __shared__ __align__(16) bf16 sQ[64 * 136], sK[64 * 136], sV[64 * 136];
  __shared__ float smn[128];
  int n0 = blockIdx.x * 64, h = blockIdx.y, b = blockIdx.z;
  size_t bh = (size_t)b * H_ + h;
  int t = threadIdx.x;
#pragma unroll
  for (int p = 0; p < 4; p++) {
    int i = p * 256 + t;            // 1024 uint4 per plane
    int row = i >> 4, c16 = i & 15;
    size_t base = ((size_t)b * N_ + n0 + row) * NO_ + (size_t)h * DH_;
    ((uint4*)sQ)[row * 17 + c16] = *((const uint4*)(qkv + base) + c16);
    ((uint4*)sK)[row * 17 + c16] = *((const uint4*)(qkv + base + D_) + c16);
    ((uint4*)sV)[row * 17 + c16] = *((const uint4*)(qkv + base + 2 * D_) + c16);
  }
  if (t < 128) smn[t] = mem_norm[bh * DH_ + t];
  __syncthreads();
  int row = t >> 1, h2 = t & 1, d0 = h2 * 64;
  int n = n0 + row;
  float sq = 0.f, sk = 0.f;
  const float cexp = 13.287712379549449f / 128.0f;  // log2(10000)/128
#pragma unroll 2
  for (int c = 0; c < 8; c++) {
    bf16x8 q8 = *(const bf16x8*)(sQ + row * 136 + d0 + c * 8);
    bf16x8 k8 = *(const bf16x8*)(sK + row * 136 + d0 + c * 8);
    bf16x8 qo, ko, kf8;
#pragma unroll
    for (int e = 0; e < 8; e += 2) {
      int d = d0 + c * 8 + e;
      float invf = exp2f(-(float)d * cexp);
      float ang = (float)n * invf;
      float sn, cs;
      __sincosf(ang, &sn, &cs);
      float qx = (float)q8[e] * SCALE_, qy = (float)q8[e + 1] * SCALE_;
      qo[e]     = (bf16)(qx * cs - qy * sn);
      qo[e + 1] = (bf16)(qy * cs + qx * sn);
      float kx = (float)k8[e], ky = (float)k8[e + 1];
      ko[e]     = (bf16)(kx * cs - ky * sn);
      ko[e + 1] = (bf16)(ky * cs + kx * sn);
      float f0 = elu1(kx), f1 = elu1(ky);
      kf8[e] = (bf16)f0; kf8[e + 1] = (bf16)f1;
      sk += f0 * smn[d] + f1 * smn[d + 1];
      sq += elu1((float)q8[e]) * smn[d] + elu1((float)q8[e + 1]) * smn[d + 1];
    }
    *(bf16x8*)(qr + (bh * N_ + n) * DH_ + d0 + c * 8) = qo;
    *(bf16x8*)(kr + (bh * N_ + n) * DH_ + d0 + c * 8) = ko;
    *(bf16x8*)(sK + row * 136 + d0 + c * 8) = kf8;  // in place; region owned by this thread
  }
  sq += __shfl_xor(sq, 1);
  sk += __shfl_xor(sk, 1);
  if (h2 == 0) { qden[bh * N_ + n] = sq; kden[bh * N_ + n] = sk; }
  __syncthreads();
  // transpose out: kfT, vT rows d (128), cols n (64)
  int d = t >> 1, part = t & 1;
#pragma unroll
  for (int v8 = 0; v8 < 4; v8++) {
    bf16x8 okf, ov;
#pragma unroll
    for (int e = 0; e < 8; e++) {
      int nn = part * 32 + v8 * 8 + e;
      okf[e] = sK[nn * 136 + d];
      ov[e]  = sV[nn * 136 + d];
    }
    size_t o = (bh * DH_ + d) * N_ + n0 + part * 32 + v8 * 8;
    *(bf16x8*)(kfT + o) = okf;
    *(bf16x8*)(vT + o)  = ov;
  }
}

// ------- flash attention, K-chunked (flash-decoding style) -------
// Swapped-operand MFMA + K-permuted staging (P never touches LDS).
// Chunk = 4 kv-tiles (uniform block duration -> higher avg occupancy).
__global__ __launch_bounds__(256) void k_attn2(const bf16* __restrict__ qr,
                                               const bf16* __restrict__ kr,
                                               const bf16* __restrict__ vT,
                                               bf16* __restrict__ attn_out,
                                               bf16* __restrict__ pO,
                                               float* __restrict__ pstat) {
  __shared__ __align__(16) bf16 sK[64 * 128];
  __shared__ __align__(16) bf16 sV[128 * 64];
  // bijective XCD swizzle: 2304 = 8 * 288, contiguous 288-block chunk per XCD
  int L = blockIdx.x;
  int x = (L & 7) * 288 + (L >> 3);
  size_t bh = x / 144;
  int e = x % 144;
  int qt, c;   // qt: 64-row q tile (0..31); c: 4-tile kv chunk
  if (e < 32)       { qt = 31 - (e >> 3); c = e & 7; }
  else if (e < 60)  { int u = e - 32;  qt = 27 - u / 7; c = u % 7; }
  else if (e < 84)  { int u = e - 60;  qt = 23 - u / 6; c = u % 6; }
  else if (e < 104) { int u = e - 84;  qt = 19 - u / 5; c = u % 5; }
  else if (e < 120) { int u = e - 104; qt = 15 - (u >> 2); c = u & 3; }
  else if (e < 132) { int u = e - 120; qt = 11 - u / 3; c = u % 3; }
  else if (e < 140) { int u = e - 132; qt = 7 - (u >> 1); c = u & 1; }
  else              { qt = 3 - (e - 140); c = 0; }
  int jt0 = c * 4;
  int jt1 = min(jt0 + 4, qt + 1);

  int t = threadIdx.x;
  int w = t >> 6, lane = t & 63, quad = lane >> 4, l16 = lane & 15;
  int qlo = qt * 64 + w * 16;

  bf16x8 qfrag[4];
  const bf16* qrow = qr + (bh * N_ + qlo + l16) * DH_;
#pragma unroll
  for (int s = 0; s < 4; s++) qfrag[s] = *(const bf16x8*)(qrow + s * 32 + quad * 8);

  f32x4 zf = {0.f, 0.f, 0.f, 0.f};
  f32x4 o[8];
#pragma unroll
  for (int i = 0; i < 8; i++) o[i] = zf;
  float mrow = -1e30f, lrow = 0.f;

  // per-lane swizzled staging source offsets (tile-local)
  int krow = lane >> 4, kc16 = lane & 15;   // K: 4 rows x 16 chunks per issue
  int vrow = lane >> 3, vc8 = lane & 7;     // V: 8 rows x 8 chunks per issue

  for (int jt = jt0; jt < jt1; jt++) {
    __syncthreads();   // all waves done reading previous tile
    // K tile: 64 rows x 128 elems; wave w stages physical rows w*16..w*16+15.
    // Physical row p holds global row g(p): bit-perm (p5, p3,p2, p4, p1,p0).
#pragma unroll
    for (int j = 0; j < 4; j++) {
      int prow = w * 16 + j * 4 + krow;
      int grow = (prow & 32) | ((prow & 12) << 1) | ((prow & 16) >> 2) | (prow & 3);
      const bf16* src = kr + (bh * N_ + (size_t)jt * 64 + grow) * DH_ + (kc16 ^ (prow & 7)) * 8;
      gl_lds16(src, sK + (w * 16 + j * 4) * 128);
    }
    // V tile: 128 rows x 64 elems; wave w stages rows w*32..w*32+31
#pragma unroll
    for (int j = 0; j < 4; j++) {
      int row = w * 32 + j * 8 + vrow;
      const bf16* src = vT + (bh * DH_ + row) * N_ + (size_t)jt * 64 + (vc8 ^ (row & 7)) * 8;
      gl_lds16(src, sV + (w * 32 + j * 8) * 64);
    }
    __syncthreads();

    // QK^T swapped: sf[nt][r] = P[kpos=(nt>>1)*32+quad*8+(nt&1)*4+r][q=qlo+l16]
    f32x4 sf[4];
#pragma unroll
    for (int nt = 0; nt < 4; nt++) sf[nt] = zf;
    __builtin_amdgcn_s_setprio(1);
#pragma unroll
    for (int s = 0; s < 4; s++) {
#pragma unroll
      for (int nt = 0; nt < 4; nt++) {
        int row = nt * 16 + l16;
        bf16x8 kf = *(const bf16x8*)(sK + row * 128 + ((s * 32 + quad * 8) ^ ((row & 7) << 3)));
        sf[nt] = mfma16(kf, qfrag[s], sf[nt]);
      }
    }
    __builtin_amdgcn_s_setprio(0);
    if (jt == qt) {
      int qg = qlo + l16;
#pragma unroll
      for (int nt = 0; nt < 4; nt++) {
        int kb = jt * 64 + ((nt >> 1) << 5) + (quad << 3) + ((nt & 1) << 2);
#pragma unroll
        for (int r = 0; r < 4; r++) {
          if (kb + r > qg) sf[nt][r] = -1e30f;
        }
      }
    }
    // lane-local online softmax for q-row (qlo + l16)
    float tm = -1e30f;
#pragma unroll
    for (int nt = 0; nt < 4; nt++)
#pragma unroll
      for (int r = 0; r < 4; r++) tm = fmaxf(tm, sf[nt][r]);
    tm = fmaxf(tm, __shfl_xor(tm, 16));
    tm = fmaxf(tm, __shfl_xor(tm, 32));
    float mn = fmaxf(mrow, tm);
    float alpha = __expf(mrow - mn);
    float rs = 0.f;
#pragma unroll
    for (int nt = 0; nt < 4; nt++)
#pragma unroll
      for (int r = 0; r < 4; r++) {
        float p = __expf(sf[nt][r] - mn);
        sf[nt][r] = p;
        rs += p;
      }
    rs += __shfl_xor(rs, 16);
    rs += __shfl_xor(rs, 32);
    lrow = lrow * alpha + rs;
    mrow = mn;
#pragma unroll
    for (int i = 0; i < 8; i++) {
      o[i][0] *= alpha; o[i][1] *= alpha;
      o[i][2] *= alpha; o[i][3] *= alpha;
    }
    // pa fragments: pure in-lane packs (kpos of sf matches B-fragment layout)
    bf16x8 pa0, pa1;
#pragma unroll
    for (int r = 0; r < 4; r++) {
      pa0[r]     = (bf16)sf[0][r];
      pa0[4 + r] = (bf16)sf[1][r];
      pa1[r]     = (bf16)sf[2][r];
      pa1[4 + r] = (bf16)sf[3][r];
    }
    // PV swapped: o[vt] = O^T[v = vt*16+quad*4+r][q = l16]
    __builtin_amdgcn_s_setprio(1);
#pragma unroll
    for (int vt = 0; vt < 8; vt++) {
      int row0 = vt * 16 + l16;
      bf16x8 b0 = *(const bf16x8*)(sV + row0 * 64 + ((quad * 8) ^ ((row0 & 7) << 3)));
      bf16x8 b1 = *(const bf16x8*)(sV + row0 * 64 + ((32 + quad * 8) ^ ((row0 & 7) << 3)));
      o[vt] = mfma16(b0, pa0, o[vt]);
      o[vt] = mfma16(b1, pa1, o[vt]);
    }
    __builtin_amdgcn_s_setprio(0);
  }

  if (qt < 4) {
    float inv = 1.f / lrow;
    int qg = qlo + l16;
#pragma unroll
    for (int vt = 0; vt < 8; vt++) {
      bf16x4 ov;
#pragma unroll
      for (int r = 0; r < 4; r++) ov[r] = (bf16)(o[vt][r] * inv);
      *(bf16x4*)(attn_out + (bh * N_ + qg) * DH_ + vt * 16 + quad * 4) = ov;
    }
  } else {
    // dense cid: prefix(qt) = S(qt) - 4, S(4j+r) = 2j(j+1) + r(j+1)
    int j4 = qt >> 2, r4 = qt & 3;
    int prefix = 2 * j4 * (j4 + 1) + r4 * (j4 + 1) - 4;
    int cid = (int)bh * 140 + prefix + c;
    int lr = w * 16 + l16;
    if (quad == 0) {
      float2 st = {mrow, lrow};
      *(float2*)(pstat + ((size_t)cid * 64 + lr) * 2) = st;
    }
#pragma unroll
    for (int vt = 0; vt < 8; vt++) {
      bf16x4 ov;
#pragma unroll
      for (int r = 0; r < 4; r++) ov[r] = (bf16)o[vt][r];
      *(bf16x4*)(pO + ((size_t)cid * 64 + lr) * DH_ + vt * 16 + quad * 4) = ov;
    }
  }
}

// ------- MFMA retrieval + gate-combine + vnew (emits vnT d-major).
//         Flash-decoding combine for qt>=4 (up to 8 chunks) done in a
//         vectorized phase staged into sVn LDS; gate loop reads scalar LDS. -------
#define SMT_STRIDE 136
#define VNSTR 138
__global__ __launch_bounds__(256) void k_retrieve2(const bf16* __restrict__ qkv,
                                                   const bf16* __restrict__ mkvT,
                                                   const float* __restrict__ qden,
                                                   const float* __restrict__ kden,
                                                   const bf16* __restrict__ attn,
                                                   const bf16* __restrict__ pO,
                                                   const float* __restrict__ pstat,
                                                   const float* __restrict__ hg,
                                                   bf16* __restrict__ comb,
                                                   bf16* __restrict__ vnT) {
  __shared__ __align__(16) bf16 smT[DH_ * SMT_STRIDE];
  __shared__ __align__(16) bf16 sVn[64 * VNSTR];
  int h = blockIdx.y, b = blockIdx.z;
  size_t bh = (size_t)b * H_ + h;
  int t = threadIdx.x;
  int w = t >> 6, lane = t & 63, quad = lane >> 4, l16 = lane & 15;
  int qt = blockIdx.x;
  int n0 = qt * 64;

  {
    const uint4* src = (const uint4*)(mkvT + bh * DH_ * DH_);
    uint4* dst = (uint4*)smT;
#pragma unroll
    for (int it = 0; it < 8; it++) {
      int i = t + it * 256;
      int row = i >> 4, col = i & 15;
      dst[row * 17 + col] = src[i];
    }
  }

  // ---- Phase A: attention output for rows n0..n0+63 -> sVn (vectorized) ----
  {
    int row = t >> 2, dseg = (t & 3) * 32;
    bf16* dst = sVn + row * VNSTR + dseg;
    if (qt < 4) {
      const bf16x8* p = (const bf16x8*)(attn + ((size_t)bh * N_ + n0 + row) * DH_ + dseg);
#pragma unroll
      for (int j = 0; j < 4; j++) *(bf16x8*)(dst + j * 8) = p[j];
    } else {
      int nch = (qt + 4) >> 2;   // ceil((qt+1)/4), 2..8
      int j4 = qt >> 2, r4 = qt & 3;
      int cidb = (int)bh * 140 + 2 * j4 * (j4 + 1) + r4 * (j4 + 1) - 4;
      float ms[8], ls[8];
      float mg = -1e30f;
#pragma unroll 8
      for (int c = 0; c < nch; c++) {
        float2 st = *(const float2*)(pstat + ((size_t)(cidb + c) * 64 + row) * 2);
        ms[c] = st.x; ls[c] = st.y;
        mg = fmaxf(mg, st.x);
      }
      float L = 0.f, wcf[8];
#pragma unroll 8
      for (int c = 0; c < nch; c++) { wcf[c] = __expf(ms[c] - mg); L += ls[c] * wcf[c]; }
      float inv = 1.f / L;
      float acc[32];
#pragma unroll
      for (int i = 0; i < 32; i++) acc[i] = 0.f;
#pragma unroll 8
      for (int c = 0; c < nch; c++) {
        const bf16x8* p = (const bf16x8*)(pO + ((size_t)(cidb + c) * 64 + row) * DH_ + dseg);
#pragma unroll
        for (int j = 0; j < 4; j++) {
          bf16x8 v = p[j];
#pragma unroll
          for (int e2 = 0; e2 < 8; e2++) acc[j * 8 + e2] += wcf[c] * (float)v[e2];
        }
      }
#pragma unroll
      for (int j = 0; j < 4; j++) {
        bf16x8 ov;
#pragma unroll
        for (int e2 = 0; e2 < 8; e2++) ov[e2] = (bf16)(acc[j * 8 + e2] * inv);
        *(bf16x8*)(dst + j * 8) = ov;
      }
    }
  }

  int nrow = n0 + w * 16 + l16;
  const bf16* base = qkv + ((size_t)b * N_ + nrow) * NO_ + h * DH_;
  bf16x8 qa[4], ka[4];
#pragma unroll
  for (int s = 0; s < 4; s++) {
    int k0 = s * 32 + quad * 8;
    bf16x8 q8 = *(const bf16x8*)(base + k0);
    bf16x8 k8 = *(const bf16x8*)(base + D_ + k0);
    bf16x8 qo, ko;
#pragma unroll
    for (int e2 = 0; e2 < 8; e2++) {
      qo[e2] = (bf16)elu1((float)q8[e2]);
      ko[e2] = (bf16)elu1((float)k8[e2]);
    }
    qa[s] = qo; ka[s] = ko;
  }

  __syncthreads();   // smT + sVn (phase A) ready
  f32x4 zf = {0.f, 0.f, 0.f, 0.f};
  f32x4 accq[8], acck[8];
#pragma unroll
  for (int vt = 0; vt < 8; vt++) { accq[vt] = zf; acck[vt] = zf; }
#pragma unroll
  for (int vt = 0; vt < 8; vt++) {
#pragma unroll
    for (int s = 0; s < 4; s++) {
      bf16x8 bfr = *(const bf16x8*)(smT + (vt * 16 + l16) * SMT_STRIDE + s * 32 + quad * 8);
      accq[vt] = mfma16(qa[s], bfr, accq[vt]);
      acck[vt] = mfma16(ka[s], bfr, acck[vt]);
    }
  }

  float g = 1.f / (1.f + __expf(-hg[h]));
#pragma unroll
  for (int r = 0; r < 4; r++) {
    int nl = w * 16 + quad * 4 + r;
    int n = n0 + nl;
    size_t m = (size_t)b * N_ + n;
    float qd = fmaxf(qden[bh * N_ + n], 1e-10f);
    float kd = fmaxf(kden[bh * N_ + n], 1e-10f);
#pragma unroll
    for (int vt = 0; vt < 8; vt++) {
      int v = vt * 16 + l16;
      float mo = accq[vt][r] / qd;
      float ov = (float)sVn[nl * VNSTR + v];   // combined attention (LDS)
      comb[m * D_ + h * DH_ + v] = (bf16)(ov * g + mo * (1.f - g));
      float vv = (float)qkv[m * NO_ + 2 * D_ + h * DH_ + v];
      // each (nl,v) location is read & written by exactly this thread
      sVn[nl * VNSTR + v] = (bf16)(vv - acck[vt][r] / kd);
    }
  }
  __syncthreads();
  // transpose out vnT: rows v (128), cols n (64)
  int d = t >> 1, part = t & 1;
#pragma unroll
  for (int v8 = 0; v8 < 4; v8++) {
    bf16x8 ov;
#pragma unroll
    for (int e2 = 0; e2 < 8; e2++) ov[e2] = sVn[(part * 32 + v8 * 8 + e2) * VNSTR + d];
    *(bf16x8*)(vnT + (bh * DH_ + d) * N_ + n0 + part * 32 + v8 * 8) = ov;
  }
}

// ------- tail: out-projection GEMM (blocks 0..255) | new_kv+norm (256..511) -------
#define GSTR 40
__global__ __launch_bounds__(256) void k_tail(const bf16* __restrict__ comb,
                                              const bf16* __restrict__ wob,
                                              float* __restrict__ out,
                                              const bf16* __restrict__ kfT,
                                              const bf16* __restrict__ vnT,
                                              float* __restrict__ out_kv,
                                              float* __restrict__ out_norm) {
  __shared__ __align__(16) bf16 sA[128 * 64];
  __shared__ __align__(16) bf16 sB[128 * 64];
  int t = threadIdx.x;
  if (blockIdx.x < 256) {
    // out GEMM: M=4096, N=1024, K=1024; grid 8x32, XCD swizzle
    int lin = blockIdx.x;
    int swz = (lin & 7) * 32 + (lin >> 3);
    int bx = swz % 8, by = swz / 8;
    gemm_body<float>(comb, wob, out, D_, D_, by * 128, bx * 128, sA, sB, t);
  } else {
    int i = blockIdx.x - 256;
    int kx = i & 15, h = (i >> 4) & 7, b = i >> 7;
    int w = t >> 6, lane = t & 63, quad = lane >> 4, l16 = lane & 15;
    size_t bh = (size_t)b * H_ + h;
    const bf16* A  = kfT + bh * DH_ * N_;
    const bf16* Bm = vnT + bh * DH_ * N_;
    int wr = (w & 1) * 64, wc = (w >> 1) * 64;
    f32x4 zf = {0.f, 0.f, 0.f, 0.f};
    f32x4 acc[4][4];
#pragma unroll
    for (int a = 0; a < 4; a++)
#pragma unroll
      for (int c = 0; c < 4; c++) acc[a][c] = zf;
    int trow = t >> 2, tc = t & 3;
    float sn0 = 0.f, sn1 = 0.f;    // partial kf row-sums (rows trow, trow+64)
    int kend = (kx + 1) * 128;
    for (int k0 = kx * 128; k0 < kend; k0 += 32) {
      __syncthreads();
      uint4 va0 = *((const uint4*)(A + (size_t)trow * N_ + k0) + tc);
      uint4 va1 = *((const uint4*)(A + (size_t)(trow + 64) * N_ + k0) + tc);
      ((uint4*)sA)[trow * 5 + tc]        = va0;
      ((uint4*)sA)[(trow + 64) * 5 + tc] = va1;
      ((uint4*)sB)[trow * 5 + tc]        = *((const uint4*)(Bm + (size_t)trow * N_ + k0) + tc);
      ((uint4*)sB)[(trow + 64) * 5 + tc] = *((const uint4*)(Bm + (size_t)(trow + 64) * N_ + k0) + tc);
      bf16x8 x0 = *(bf16x8*)&va0, x1 = *(bf16x8*)&va1;
#pragma unroll
      for (int e = 0; e < 8; e++) { sn0 += (float)x0[e]; sn1 += (float)x1[e]; }
      __syncthreads();
      bf16x8 af[4], bfr[4];
#pragma unroll
      for (int mt = 0; mt < 4; mt++)
        af[mt] = *(const bf16x8*)(sA + (wr + mt * 16 + l16) * GSTR + quad * 8);
#pragma unroll
      for (int nt = 0; nt < 4; nt++)
        bfr[nt] = *(const bf16x8*)(sB + (wc + nt * 16 + l16) * GSTR + quad * 8);
#pragma unroll
      for (int mt = 0; mt < 4; mt++)
#pragma unroll
        for (int nt = 0; nt < 4; nt++)
          acc[mt][nt] = mfma16(af[mt], bfr[nt], acc[mt][nt]);
    }
    sn0 += __shfl_xor(sn0, 1); sn0 += __shfl_xor(sn0, 2);
    sn1 += __shfl_xor(sn1, 1); sn1 += __shfl_xor(sn1, 2);
    if (tc == 0) {
      atomicAdd(out_norm + bh * DH_ + trow, sn0);
      atomicAdd(out_norm + bh * DH_ + trow + 64, sn1);
    }
    float* obh = out_kv + bh * DH_ * DH_;
#pragma unroll
    for (int mt = 0; mt < 4; mt++)
#pragma unroll
      for (int nt = 0; nt < 4; nt++) {
        int row = wr + mt * 16 + quad * 4;
        int col = wc + nt * 16 + l16;
#pragma unroll
        for (int r = 0; r < 4; r++)
          atomicAdd(obh + (size_t)(row + r) * DH_ + col, acc[mt][nt][r]);
      }
  }
}

extern "C" void kernel_launch(void* const* d_in, const int* in_sizes, int n_in,
                              void* d_out, int out_size, void* d_ws, size_t ws_size,
                              hipStream_t stream) {
  const float* x        = (const float*)d_in[0];
  const float* gamma    = (const float*)d_in[1];
  const float* w_qkv    = (const float*)d_in[2];
  const float* w_out    = (const float*)d_in[3];
  const float* hg       = (const float*)d_in[4];
  const float* mem_kv   = (const float*)d_in[5];
  const float* mem_norm = (const float*)d_in[6];
  float* out      = (float*)d_out;
  float* out_kv   = out + (size_t)B_ * N_ * D_;
  float* out_norm = out_kv + (size_t)B_ * H_ * DH_ * DH_;

  char* ws = (char*)d_ws;
  size_t off = 0;
  auto alloc = [&](size_t bytes) -> void* {
    void* p = ws + off;
    off += (bytes + 255) & ~(size_t)255;
    return p;
  };
  bf16*  xn   = (bf16*)alloc((size_t)B_ * N_ * D_ * 2);
  bf16*  wqb  = (bf16*)alloc((size_t)NO_ * D_ * 2);
  bf16*  wob  = (bf16*)alloc((size_t)D_ * D_ * 2);
  bf16*  qkvb = (bf16*)alloc((size_t)B_ * N_ * NO_ * 2);
  bf16*  qr   = (bf16*)alloc((size_t)B_ * H_ * N_ * DH_ * 2);
  bf16*  kr   = (bf16*)alloc((size_t)B_ * H_ * N_ * DH_ * 2);
  bf16*  vT   = (bf16*)alloc((size_t)B_ * H_ * DH_ * N_ * 2);
  bf16*  kfT  = (bf16*)alloc((size_t)B_ * H_ * DH_ * N_ * 2);  // written early (prep2)
  float* qden = (float*)alloc((size_t)B_ * H_ * N_ * 4);
  float* kden = (float*)alloc((size_t)B_ * H_ * N_ * 4);
  bf16*  attnb= (bf16*)alloc((size_t)B_ * H_ * N_ * DH_ * 2);
  bf16*  mkvT = (bf16*)alloc((size_t)B_ * H_ * DH_ * DH_ * 2);
  bf16*  pO    = (bf16*)alloc((size_t)2240 * 64 * DH_ * 2);    // 16 bh * 140 cids
  float* pstat = (float*)alloc((size_t)2240 * 64 * 2 * 4);
  // Aliases (timeline-checked): comb reuses xn (dead after qkv-GEMM);
  // vnT reuses kr (dead after attn2; retrieve2 runs strictly after).
  bf16*  comb = xn;
  bf16*  vnT  = kr;
  (void)in_sizes; (void)n_in; (void)out_size; (void)ws_size;

  k_front<<<dim3(2 * B_ * N_ + B_ * H_), 256, 0, stream>>>(
      x, gamma, xn,
      (const float4*)w_qkv, (bf16x4*)wqb, NO_ * D_ / 4,
      (const float4*)w_out, (bf16x4*)wob, D_ * D_ / 4,
      mem_kv, mem_norm, mkvT, out_kv, out_norm);
  k_gemm_qkv<<<dim3(NO_ / 128, B_ * N_ / 128), 256, 0, stream>>>(xn, wqb, qkvb, NO_, D_);
  k_prep2<<<dim3(N_ / 64, H_, B_), 256, 0, stream>>>(qkvb, mem_norm, qr, kr, vT, kfT, qden, kden);
  k_attn2<<<dim3(2304), 256, 0, stream>>>(qr, kr, vT, attnb, pO, pstat);
  k_retrieve2<<<dim3(N_ / 64, H_, B_), 256, 0, stream>>>(qkvb, mkvT, qden, kden, attnb, pO, pstat, hg, comb, vnT);
  k_tail<<<dim3(512), 256, 0, stream>>>(comb, wob, out, kfT, vnT, out_kv, out_norm);
}

// Round 17
// 239.708 us; speedup vs baseline: 1.0408x; 1.0408x over previous
//
#include <hip/hip_runtime.h>
#include <hip/hip_bf16.h>

#define B_ 2
#define N_ 2048
#define H_ 8
#define DH_ 128
#define D_ 1024
#define NO_ 3072
#define SCALE_ 0.08838834764831845f

typedef __bf16 bf16;
typedef __bf16 bf16x4 __attribute__((ext_vector_type(4)));
typedef __bf16 bf16x8 __attribute__((ext_vector_type(8)));
typedef float f32x4 __attribute__((ext_vector_type(4)));

__device__ inline f32x4 mfma16(bf16x8 a, bf16x8 b, f32x4 c) {
  return __builtin_amdgcn_mfma_f32_16x16x32_bf16(a, b, c, 0, 0, 0);
}

__device__ inline float elu1(float x) { return x > 0.f ? x + 1.f : __expf(x); }

// async global->LDS 16B: lds dest = wave-uniform base + lane*16
__device__ inline void gl_lds16(const bf16* g, bf16* l) {
  __builtin_amdgcn_global_load_lds(
      (const __attribute__((address_space(1))) unsigned int*)g,
      (__attribute__((address_space(3))) unsigned int*)l, 16, 0, 0);
}

// --- shared GEMM body: C[M][N] = A[M][K] @ B[N][K]^T; BK=64, XOR-swizzled
//     LDS (content swizzle on the per-lane GLOBAL source of global_load_lds;
//     reads use the same involution). ---
template <typename OT>
__device__ inline void gemm_body(const bf16* __restrict__ A, const bf16* __restrict__ B,
                                 OT* __restrict__ C, int Nn, int K, int m0, int n0,
                                 bf16* sA, bf16* sB, int t) {
  int w = t >> 6, lane = t & 63, quad = lane >> 4, l16 = lane & 15;
  int wr = (w & 1) * 64, wc = (w >> 1) * 64;
  f32x4 zf = {0.f, 0.f, 0.f, 0.f};
  f32x4 acc[4][4];
#pragma unroll
  for (int a = 0; a < 4; a++)
#pragma unroll
    for (int c = 0; c < 4; c++) acc[a][c] = zf;
  int r8 = lane >> 3, c8 = lane & 7;   // 8 rows x 8 16B-chunks per issue
  for (int k0 = 0; k0 < K; k0 += 64) {
    __syncthreads();
#pragma unroll
    for (int j = 0; j < 4; j++) {
      int prow = w * 32 + j * 8 + r8;
      int co = (c8 ^ (prow & 7)) * 8;
      gl_lds16(A + (size_t)(m0 + prow) * K + k0 + co, sA + (w * 32 + j * 8) * 64);
      gl_lds16(B + (size_t)(n0 + prow) * K + k0 + co, sB + (w * 32 + j * 8) * 64);
    }
    __syncthreads();
#pragma unroll
    for (int ks = 0; ks < 2; ks++) {
      bf16x8 af[4], bfr[4];
#pragma unroll
      for (int mt = 0; mt < 4; mt++) {
        int row = wr + mt * 16 + l16;
        af[mt] = *(const bf16x8*)(sA + row * 64 + ((ks * 32 + quad * 8) ^ ((row & 7) << 3)));
      }
#pragma unroll
      for (int nt = 0; nt < 4; nt++) {
        int row = wc + nt * 16 + l16;
        bfr[nt] = *(const bf16x8*)(sB + row * 64 + ((ks * 32 + quad * 8) ^ ((row & 7) << 3)));
      }
#pragma unroll
      for (int mt = 0; mt < 4; mt++)
#pragma unroll
        for (int nt = 0; nt < 4; nt++)
          acc[mt][nt] = mfma16(af[mt], bfr[nt], acc[mt][nt]);
    }
  }
#pragma unroll
  for (int mt = 0; mt < 4; mt++)
#pragma unroll
    for (int nt = 0; nt < 4; nt++) {
      int row = m0 + wr + mt * 16 + quad * 4;
      int col = n0 + wc + nt * 16 + l16;
      OT* cp = C + (size_t)row * Nn + col;
#pragma unroll
      for (int r = 0; r < 4; r++) cp[(size_t)r * Nn] = (OT)acc[mt][nt][r];
    }
}

// ------- front: rmsnorm (blocks 0..4095) | weight cvt (4096..8191) |
//         mkvT + out_kv/out_norm init (8192..8207) -------
__global__ __launch_bounds__(256) void k_front(const float* __restrict__ x,
                                               const float* __restrict__ gamma,
                                               bf16* __restrict__ xn,
                                               const float4* __restrict__ wa, bf16x4* __restrict__ oa, int na4,
                                               const float4* __restrict__ wb, bf16x4* __restrict__ ob, int nb4,
                                               const float* __restrict__ mem_kv,
                                               const float* __restrict__ mem_norm,
                                               bf16* __restrict__ mkvT,
                                               float* __restrict__ out_kv,
                                               float* __restrict__ out_norm) {
  int blk = blockIdx.x;
  int t = threadIdx.x;
  if (blk < B_ * N_) {
    // ---- RMSNorm row ----
    int row = blk;
    const float4* xr = (const float4*)(x + (size_t)row * D_);
    float4 xv = xr[t];
    float ss = xv.x*xv.x + xv.y*xv.y + xv.z*xv.z + xv.w*xv.w;
#pragma unroll
    for (int m = 1; m < 64; m <<= 1) ss += __shfl_xor(ss, m);
    __shared__ float sred[4];
    if ((t & 63) == 0) sred[t >> 6] = ss;
    __syncthreads();
    float tot = sred[0] + sred[1] + sred[2] + sred[3];
    float scale = 32.0f / fmaxf(sqrtf(tot), 1e-12f);
    float4 gv = ((const float4*)gamma)[t];
    bf16x4 ov;
    ov[0] = (bf16)(xv.x * scale * gv.x);
    ov[1] = (bf16)(xv.y * scale * gv.y);
    ov[2] = (bf16)(xv.z * scale * gv.z);
    ov[3] = (bf16)(xv.w * scale * gv.w);
    *(bf16x4*)(xn + (size_t)row * D_ + t * 4) = ov;
  } else if (blk < 2 * B_ * N_) {
    // ---- weight fp32->bf16 ----
    int i = (blk - B_ * N_) * 256 + t;
    if (i < na4) {
      float4 v = wa[i];
      bf16x4 o;
      o[0] = (bf16)v.x; o[1] = (bf16)v.y; o[2] = (bf16)v.z; o[3] = (bf16)v.w;
      oa[i] = o;
    } else {
      int j = i - na4;
      if (j < nb4) {
        float4 v = wb[j];
        bf16x4 o;
        o[0] = (bf16)v.x; o[1] = (bf16)v.y; o[2] = (bf16)v.z; o[3] = (bf16)v.w;
        ob[j] = o;
      }
    }
  } else {
    // ---- mkvT transpose + out_kv/out_norm init ----
    int bh = blk - 2 * B_ * N_;
    int v = t & 127, khalf = t >> 7;
    const float* src = mem_kv + (size_t)bh * DH_ * DH_;
    bf16* dst = mkvT + (size_t)bh * DH_ * DH_ + (size_t)v * DH_ + khalf * 64;
#pragma unroll
    for (int kk8 = 0; kk8 < 8; kk8++) {
      int k0 = khalf * 64 + kk8 * 8;
      bf16x8 o;
#pragma unroll
      for (int e = 0; e < 8; e++) o[e] = (bf16)src[(size_t)(k0 + e) * DH_ + v];
      *(bf16x8*)(dst + kk8 * 8) = o;
    }
    const float4* s4 = (const float4*)src;
    float4* d4 = (float4*)(out_kv + (size_t)bh * DH_ * DH_);
#pragma unroll
    for (int i = 0; i < 16; i++) d4[t + i * 256] = s4[t + i * 256];
    if (t < DH_) out_norm[(size_t)bh * DH_ + t] = mem_norm[(size_t)bh * DH_ + t];
  }
}

// --- qkv GEMM launcher (bijective XCD swizzle via gridDim) ---
__global__ __launch_bounds__(256) void k_gemm_qkv(const bf16* __restrict__ A,
                                                  const bf16* __restrict__ B,
                                                  bf16* __restrict__ C,
                                                  int Nn, int K) {
  __shared__ __align__(16) bf16 sA[128 * 64];
  __shared__ __align__(16) bf16 sB[128 * 64];
  int lin = blockIdx.y * gridDim.x + blockIdx.x;
  int cpx = (gridDim.x * gridDim.y) >> 3;
  int swz = (lin & 7) * cpx + (lin >> 3);
  int bx = swz % gridDim.x, by = swz / gridDim.x;
  gemm_body<bf16>(A, B, C, Nn, K, by * 128, bx * 128, sA, sB, threadIdx.x);
}

// --- prep2: 64 tokens x 1 head per block. RoPE(q,k) -> qr,kr (n-major);
//     kf,v -> kfT,vT (d-major via LDS transpose); qden/kden reductions. ---
__global__ __launch_bounds__(256) void k_prep2(const bf16* __restrict__ qkv,
                                               const float* __restrict__ mem_norm,
                                               bf16* __restrict__ qr, bf16* __restrict__ kr,
                                               bf16* __restrict__ vT, bf16* __restrict__ kfT,
                                               float* __restrict__ qden, float* __restrict__ kden) {
  __shared__ __align__(16) bf16 sQ[64 * 136], sK[64 * 136], sV[64 * 136];
  __shared__ float smn[128];
  int n0 = blockIdx.x * 64, h = blockIdx.y, b = blockIdx.z;
  size_t bh = (size_t)b * H_ + h;
  int t = threadIdx.x;
#pragma unroll
  for (int p = 0; p < 4; p++) {
    int i = p * 256 + t;            // 1024 uint4 per plane
    int row = i >> 4, c16 = i & 15;
    size_t base = ((size_t)b * N_ + n0 + row) * NO_ + (size_t)h * DH_;
    ((uint4*)sQ)[row * 17 + c16] = *((const uint4*)(qkv + base) + c16);
    ((uint4*)sK)[row * 17 + c16] = *((const uint4*)(qkv + base + D_) + c16);
    ((uint4*)sV)[row * 17 + c16] = *((const uint4*)(qkv + base + 2 * D_) + c16);
  }
  if (t < 128) smn[t] = mem_norm[bh * DH_ + t];
  __syncthreads();
  int row = t >> 1, h2 = t & 1, d0 = h2 * 64;
  int n = n0 + row;
  float sq = 0.f, sk = 0.f;
  const float cexp = 13.287712379549449f / 128.0f;  // log2(10000)/128
#pragma unroll 2
  for (int c = 0; c < 8; c++) {
    bf16x8 q8 = *(const bf16x8*)(sQ + row * 136 + d0 + c * 8);
    bf16x8 k8 = *(const bf16x8*)(sK + row * 136 + d0 + c * 8);
    bf16x8 qo, ko, kf8;
#pragma unroll
    for (int e = 0; e < 8; e += 2) {
      int d = d0 + c * 8 + e;
      float invf = exp2f(-(float)d * cexp);
      float ang = (float)n * invf;
      float sn, cs;
      __sincosf(ang, &sn, &cs);
      float qx = (float)q8[e] * SCALE_, qy = (float)q8[e + 1] * SCALE_;
      qo[e]     = (bf16)(qx * cs - qy * sn);
      qo[e + 1] = (bf16)(qy * cs + qx * sn);
      float kx = (float)k8[e], ky = (float)k8[e + 1];
      ko[e]     = (bf16)(kx * cs - ky * sn);
      ko[e + 1] = (bf16)(ky * cs + kx * sn);
      float f0 = elu1(kx), f1 = elu1(ky);
      kf8[e] = (bf16)f0; kf8[e + 1] = (bf16)f1;
      sk += f0 * smn[d] + f1 * smn[d + 1];
      sq += elu1((float)q8[e]) * smn[d] + elu1((float)q8[e + 1]) * smn[d + 1];
    }
    *(bf16x8*)(qr + (bh * N_ + n) * DH_ + d0 + c * 8) = qo;
    *(bf16x8*)(kr + (bh * N_ + n) * DH_ + d0 + c * 8) = ko;
    *(bf16x8*)(sK + row * 136 + d0 + c * 8) = kf8;  // in place; region owned by this thread
  }
  sq += __shfl_xor(sq, 1);
  sk += __shfl_xor(sk, 1);
  if (h2 == 0) { qden[bh * N_ + n] = sq; kden[bh * N_ + n] = sk; }
  __syncthreads();
  // transpose out: kfT, vT rows d (128), cols n (64)
  int d = t >> 1, part = t & 1;
#pragma unroll
  for (int v8 = 0; v8 < 4; v8++) {
    bf16x8 okf, ov;
#pragma unroll
    for (int e = 0; e < 8; e++) {
      int nn = part * 32 + v8 * 8 + e;
      okf[e] = sK[nn * 136 + d];
      ov[e]  = sV[nn * 136 + d];
    }
    size_t o = (bh * DH_ + d) * N_ + n0 + part * 32 + v8 * 8;
    *(bf16x8*)(kfT + o) = okf;
    *(bf16x8*)(vT + o)  = ov;
  }
}

// ------- flash attention, K-chunked (flash-decoding style) -------
// Swapped-operand MFMA + K-permuted staging (P never touches LDS).
__global__ __launch_bounds__(256) void k_attn2(const bf16* __restrict__ qr,
                                               const bf16* __restrict__ kr,
                                               const bf16* __restrict__ vT,
                                               bf16* __restrict__ attn_out,
                                               bf16* __restrict__ pO,
                                               float* __restrict__ pstat) {
  __shared__ __align__(16) bf16 sK[64 * 128];
  __shared__ __align__(16) bf16 sV[128 * 64];
  // bijective XCD swizzle: 1280 = 8 * 160, contiguous 160-block chunk per XCD
  int L = blockIdx.x;
  int x = (L & 7) * 160 + (L >> 3);
  size_t bh = x / 80;
  int e = x % 80;
  int qt, c;
  if (e < 32)      { qt = 31 - (e >> 2); c = e & 3; }
  else if (e < 56) { int u = e - 32; qt = 23 - u / 3; c = u % 3; }
  else if (e < 72) { int u = e - 56; qt = 15 - (u >> 1); c = u & 1; }
  else             { qt = 7 - (e - 72); c = 0; }
  int jt0 = c * 8;
  int jt1 = min(jt0 + 8, qt + 1);

  int t = threadIdx.x;
  int w = t >> 6, lane = t & 63, quad = lane >> 4, l16 = lane & 15;
  int qlo = qt * 64 + w * 16;

  bf16x8 qfrag[4];
  const bf16* qrow = qr + (bh * N_ + qlo + l16) * DH_;
#pragma unroll
  for (int s = 0; s < 4; s++) qfrag[s] = *(const bf16x8*)(qrow + s * 32 + quad * 8);

  f32x4 zf = {0.f, 0.f, 0.f, 0.f};
  f32x4 o[8];
#pragma unroll
  for (int i = 0; i < 8; i++) o[i] = zf;
  float mrow = -1e30f, lrow = 0.f;

  // per-lane swizzled staging source offsets (tile-local)
  int krow = lane >> 4, kc16 = lane & 15;   // K: 4 rows x 16 chunks per issue
  int vrow = lane >> 3, vc8 = lane & 7;     // V: 8 rows x 8 chunks per issue

  for (int jt = jt0; jt < jt1; jt++) {
    __syncthreads();   // all waves done reading previous tile
    // K tile: 64 rows x 128 elems; wave w stages physical rows w*16..w*16+15.
    // Physical row p holds global row g(p): bit-perm (p5, p3,p2, p4, p1,p0).
#pragma unroll
    for (int j = 0; j < 4; j++) {
      int prow = w * 16 + j * 4 + krow;
      int grow = (prow & 32) | ((prow & 12) << 1) | ((prow & 16) >> 2) | (prow & 3);
      const bf16* src = kr + (bh * N_ + (size_t)jt * 64 + grow) * DH_ + (kc16 ^ (prow & 7)) * 8;
      gl_lds16(src, sK + (w * 16 + j * 4) * 128);
    }
    // V tile: 128 rows x 64 elems; wave w stages rows w*32..w*32+31
#pragma unroll
    for (int j = 0; j < 4; j++) {
      int row = w * 32 + j * 8 + vrow;
      const bf16* src = vT + (bh * DH_ + row) * N_ + (size_t)jt * 64 + (vc8 ^ (row & 7)) * 8;
      gl_lds16(src, sV + (w * 32 + j * 8) * 64);
    }
    __syncthreads();

    // QK^T swapped: sf[nt][r] = P[kpos=(nt>>1)*32+quad*8+(nt&1)*4+r][q=qlo+l16]
    f32x4 sf[4];
#pragma unroll
    for (int nt = 0; nt < 4; nt++) sf[nt] = zf;
    __builtin_amdgcn_s_setprio(1);
#pragma unroll
    for (int s = 0; s < 4; s++) {
#pragma unroll
      for (int nt = 0; nt < 4; nt++) {
        int row = nt * 16 + l16;
        bf16x8 kf = *(const bf16x8*)(sK + row * 128 + ((s * 32 + quad * 8) ^ ((row & 7) << 3)));
        sf[nt] = mfma16(kf, qfrag[s], sf[nt]);
      }
    }
    __builtin_amdgcn_s_setprio(0);
    if (jt == qt) {
      int qg = qlo + l16;
#pragma unroll
      for (int nt = 0; nt < 4; nt++) {
        int kb = jt * 64 + ((nt >> 1) << 5) + (quad << 3) + ((nt & 1) << 2);
#pragma unroll
        for (int r = 0; r < 4; r++) {
          if (kb + r > qg) sf[nt][r] = -1e30f;
        }
      }
    }
    // lane-local online softmax for q-row (qlo + l16)
    float tm = -1e30f;
#pragma unroll
    for (int nt = 0; nt < 4; nt++)
#pragma unroll
      for (int r = 0; r < 4; r++) tm = fmaxf(tm, sf[nt][r]);
    tm = fmaxf(tm, __shfl_xor(tm, 16));
    tm = fmaxf(tm, __shfl_xor(tm, 32));
    float mn = fmaxf(mrow, tm);
    float alpha = __expf(mrow - mn);
    float rs = 0.f;
#pragma unroll
    for (int nt = 0; nt < 4; nt++)
#pragma unroll
      for (int r = 0; r < 4; r++) {
        float p = __expf(sf[nt][r] - mn);
        sf[nt][r] = p;
        rs += p;
      }
    rs += __shfl_xor(rs, 16);
    rs += __shfl_xor(rs, 32);
    lrow = lrow * alpha + rs;
    mrow = mn;
#pragma unroll
    for (int i = 0; i < 8; i++) {
      o[i][0] *= alpha; o[i][1] *= alpha;
      o[i][2] *= alpha; o[i][3] *= alpha;
    }
    // pa fragments: pure in-lane packs (kpos of sf matches B-fragment layout)
    bf16x8 pa0, pa1;
#pragma unroll
    for (int r = 0; r < 4; r++) {
      pa0[r]     = (bf16)sf[0][r];
      pa0[4 + r] = (bf16)sf[1][r];
      pa1[r]     = (bf16)sf[2][r];
      pa1[4 + r] = (bf16)sf[3][r];
    }
    // PV swapped: o[vt] = O^T[v = vt*16+quad*4+r][q = l16]
    __builtin_amdgcn_s_setprio(1);
#pragma unroll
    for (int vt = 0; vt < 8; vt++) {
      int row0 = vt * 16 + l16;
      bf16x8 b0 = *(const bf16x8*)(sV + row0 * 64 + ((quad * 8) ^ ((row0 & 7) << 3)));
      bf16x8 b1 = *(const bf16x8*)(sV + row0 * 64 + ((32 + quad * 8) ^ ((row0 & 7) << 3)));
      o[vt] = mfma16(b0, pa0, o[vt]);
      o[vt] = mfma16(b1, pa1, o[vt]);
    }
    __builtin_amdgcn_s_setprio(0);
  }

  if (qt < 8) {
    float inv = 1.f / lrow;
    int qg = qlo + l16;
#pragma unroll
    for (int vt = 0; vt < 8; vt++) {
      bf16x4 ov;
#pragma unroll
      for (int r = 0; r < 4; r++) ov[r] = (bf16)(o[vt][r] * inv);
      *(bf16x4*)(attn_out + (bh * N_ + qg) * DH_ + vt * 16 + quad * 4) = ov;
    }
  } else {
    int cid = ((int)bh * 24 + qt - 8) * 4 + c;
    int lr = w * 16 + l16;
    if (quad == 0) {
      float2 st = {mrow, lrow};
      *(float2*)(pstat + ((size_t)cid * 64 + lr) * 2) = st;
    }
#pragma unroll
    for (int vt = 0; vt < 8; vt++) {
      bf16x4 ov;
#pragma unroll
      for (int r = 0; r < 4; r++) ov[r] = (bf16)o[vt][r];
      *(bf16x4*)(pO + ((size_t)cid * 64 + lr) * DH_ + vt * 16 + quad * 4) = ov;
    }
  }
}

// ------- MFMA retrieval + gate-combine + vnew (emits vnT d-major).
//         Flash-decoding combine for qt>=8 is done in a vectorized phase
//         (k_combine's thread mapping) staged into sVn LDS; gate loop reads
//         it as scalar LDS. k_combine kernel eliminated. -------
#define SMT_STRIDE 136
#define VNSTR 138
__global__ __launch_bounds__(256) void k_retrieve2(const bf16* __restrict__ qkv,
                                                   const bf16* __restrict__ mkvT,
                                                   const float* __restrict__ qden,
                                                   const float* __restrict__ kden,
                                                   const bf16* __restrict__ attn,
                                                   const bf16* __restrict__ pO,
                                                   const float* __restrict__ pstat,
                                                   const float* __restrict__ hg,
                                                   bf16* __restrict__ comb,
                                                   bf16* __restrict__ vnT) {
  __shared__ __align__(16) bf16 smT[DH_ * SMT_STRIDE];
  __shared__ __align__(16) bf16 sVn[64 * VNSTR];
  int h = blockIdx.y, b = blockIdx.z;
  size_t bh = (size_t)b * H_ + h;
  int t = threadIdx.x;
  int w = t >> 6, lane = t & 63, quad = lane >> 4, l16 = lane & 15;
  int qt = blockIdx.x;
  int n0 = qt * 64;

  {
    const uint4* src = (const uint4*)(mkvT + bh * DH_ * DH_);
    uint4* dst = (uint4*)smT;
#pragma unroll
    for (int it = 0; it < 8; it++) {
      int i = t + it * 256;
      int row = i >> 4, col = i & 15;
      dst[row * 17 + col] = src[i];
    }
  }

  // ---- Phase A: attention output for rows n0..n0+63 -> sVn (vectorized) ----
  {
    int row = t >> 2, dseg = (t & 3) * 32;
    bf16* dst = sVn + row * VNSTR + dseg;
    if (qt < 8) {
      const bf16x8* p = (const bf16x8*)(attn + ((size_t)bh * N_ + n0 + row) * DH_ + dseg);
#pragma unroll
      for (int j = 0; j < 4; j++) *(bf16x8*)(dst + j * 8) = p[j];
    } else {
      int nch = (qt + 8) / 8;
      int cidb = ((int)bh * 24 + qt - 8) * 4;
      float ms[4], ls[4];
      float mg = -1e30f;
#pragma unroll 4
      for (int c = 0; c < nch; c++) {
        float2 st = *(const float2*)(pstat + ((size_t)(cidb + c) * 64 + row) * 2);
        ms[c] = st.x; ls[c] = st.y;
        mg = fmaxf(mg, st.x);
      }
      float L = 0.f, wcf[4];
#pragma unroll 4
      for (int c = 0; c < nch; c++) { wcf[c] = __expf(ms[c] - mg); L += ls[c] * wcf[c]; }
      float inv = 1.f / L;
      float acc[32];
#pragma unroll
      for (int i = 0; i < 32; i++) acc[i] = 0.f;
#pragma unroll 4
      for (int c = 0; c < nch; c++) {
        const bf16x8* p = (const bf16x8*)(pO + ((size_t)(cidb + c) * 64 + row) * DH_ + dseg);
#pragma unroll
        for (int j = 0; j < 4; j++) {
          bf16x8 v = p[j];
#pragma unroll
          for (int e2 = 0; e2 < 8; e2++) acc[j * 8 + e2] += wcf[c] * (float)v[e2];
        }
      }
#pragma unroll
      for (int j = 0; j < 4; j++) {
        bf16x8 ov;
#pragma unroll
        for (int e2 = 0; e2 < 8; e2++) ov[e2] = (bf16)(acc[j * 8 + e2] * inv);
        *(bf16x8*)(dst + j * 8) = ov;
      }
    }
  }

  int nrow = n0 + w * 16 + l16;
  const bf16* base = qkv + ((size_t)b * N_ + nrow) * NO_ + h * DH_;
  bf16x8 qa[4], ka[4];
#pragma unroll
  for (int s = 0; s < 4; s++) {
    int k0 = s * 32 + quad * 8;
    bf16x8 q8 = *(const bf16x8*)(base + k0);
    bf16x8 k8 = *(const bf16x8*)(base + D_ + k0);
    bf16x8 qo, ko;
#pragma unroll
    for (int e2 = 0; e2 < 8; e2++) {
      qo[e2] = (bf16)elu1((float)q8[e2]);
      ko[e2] = (bf16)elu1((float)k8[e2]);
    }
    qa[s] = qo; ka[s] = ko;
  }

  __syncthreads();   // smT + sVn (phase A) ready
  f32x4 zf = {0.f, 0.f, 0.f, 0.f};
  f32x4 accq[8], acck[8];
#pragma unroll
  for (int vt = 0; vt < 8; vt++) { accq[vt] = zf; acck[vt] = zf; }
#pragma unroll
  for (int vt = 0; vt < 8; vt++) {
#pragma unroll
    for (int s = 0; s < 4; s++) {
      bf16x8 bfr = *(const bf16x8*)(smT + (vt * 16 + l16) * SMT_STRIDE + s * 32 + quad * 8);
      accq[vt] = mfma16(qa[s], bfr, accq[vt]);
      acck[vt] = mfma16(ka[s], bfr, acck[vt]);
    }
  }

  float g = 1.f / (1.f + __expf(-hg[h]));
#pragma unroll
  for (int r = 0; r < 4; r++) {
    int nl = w * 16 + quad * 4 + r;
    int n = n0 + nl;
    size_t m = (size_t)b * N_ + n;
    float qd = fmaxf(qden[bh * N_ + n], 1e-10f);
    float kd = fmaxf(kden[bh * N_ + n], 1e-10f);
#pragma unroll
    for (int vt = 0; vt < 8; vt++) {
      int v = vt * 16 + l16;
      float mo = accq[vt][r] / qd;
      float ov = (float)sVn[nl * VNSTR + v];   // combined attention (LDS)
      comb[m * D_ + h * DH_ + v] = (bf16)(ov * g + mo * (1.f - g));
      float vv = (float)qkv[m * NO_ + 2 * D_ + h * DH_ + v];
      // each (nl,v) location is read & written by exactly this thread
      sVn[nl * VNSTR + v] = (bf16)(vv - acck[vt][r] / kd);
    }
  }
  __syncthreads();
  // transpose out vnT: rows v (128), cols n (64)
  int d = t >> 1, part = t & 1;
#pragma unroll
  for (int v8 = 0; v8 < 4; v8++) {
    bf16x8 ov;
#pragma unroll
    for (int e2 = 0; e2 < 8; e2++) ov[e2] = sVn[(part * 32 + v8 * 8 + e2) * VNSTR + d];
    *(bf16x8*)(vnT + (bh * DH_ + d) * N_ + n0 + part * 32 + v8 * 8) = ov;
  }
}

// ------- tail: out-projection GEMM (blocks 0..255) | new_kv+norm (256..511) -------
#define GSTR 40
__global__ __launch_bounds__(256) void k_tail(const bf16* __restrict__ comb,
                                              const bf16* __restrict__ wob,
                                              float* __restrict__ out,
                                              const bf16* __restrict__ kfT,
                                              const bf16* __restrict__ vnT,
                                              float* __restrict__ out_kv,
                                              float* __restrict__ out_norm) {
  __shared__ __align__(16) bf16 sA[128 * 64];
  __shared__ __align__(16) bf16 sB[128 * 64];
  int t = threadIdx.x;
  if (blockIdx.x < 256) {
    // out GEMM: M=4096, N=1024, K=1024; grid 8x32, XCD swizzle
    int lin = blockIdx.x;
    int swz = (lin & 7) * 32 + (lin >> 3);
    int bx = swz % 8, by = swz / 8;
    gemm_body<float>(comb, wob, out, D_, D_, by * 128, bx * 128, sA, sB, t);
  } else {
    int i = blockIdx.x - 256;
    int kx = i & 15, h = (i >> 4) & 7, b = i >> 7;
    int w = t >> 6, lane = t & 63, quad = lane >> 4, l16 = lane & 15;
    size_t bh = (size_t)b * H_ + h;
    const bf16* A  = kfT + bh * DH_ * N_;
    const bf16* Bm = vnT + bh * DH_ * N_;
    int wr = (w & 1) * 64, wc = (w >> 1) * 64;
    f32x4 zf = {0.f, 0.f, 0.f, 0.f};
    f32x4 acc[4][4];
#pragma unroll
    for (int a = 0; a < 4; a++)
#pragma unroll
      for (int c = 0; c < 4; c++) acc[a][c] = zf;
    int trow = t >> 2, tc = t & 3;
    float sn0 = 0.f, sn1 = 0.f;    // partial kf row-sums (rows trow, trow+64)
    int kend = (kx + 1) * 128;
    for (int k0 = kx * 128; k0 < kend; k0 += 32) {
      __syncthreads();
      uint4 va0 = *((const uint4*)(A + (size_t)trow * N_ + k0) + tc);
      uint4 va1 = *((const uint4*)(A + (size_t)(trow + 64) * N_ + k0) + tc);
      ((uint4*)sA)[trow * 5 + tc]        = va0;
      ((uint4*)sA)[(trow + 64) * 5 + tc] = va1;
      ((uint4*)sB)[trow * 5 + tc]        = *((const uint4*)(Bm + (size_t)trow * N_ + k0) + tc);
      ((uint4*)sB)[(trow + 64) * 5 + tc] = *((const uint4*)(Bm + (size_t)(trow + 64) * N_ + k0) + tc);
      bf16x8 x0 = *(bf16x8*)&va0, x1 = *(bf16x8*)&va1;
#pragma unroll
      for (int e = 0; e < 8; e++) { sn0 += (float)x0[e]; sn1 += (float)x1[e]; }
      __syncthreads();
      bf16x8 af[4], bfr[4];
#pragma unroll
      for (int mt = 0; mt < 4; mt++)
        af[mt] = *(const bf16x8*)(sA + (wr + mt * 16 + l16) * GSTR + quad * 8);
#pragma unroll
      for (int nt = 0; nt < 4; nt++)
        bfr[nt] = *(const bf16x8*)(sB + (wc + nt * 16 + l16) * GSTR + quad * 8);
#pragma unroll
      for (int mt = 0; mt < 4; mt++)
#pragma unroll
        for (int nt = 0; nt < 4; nt++)
          acc[mt][nt] = mfma16(af[mt], bfr[nt], acc[mt][nt]);
    }
    sn0 += __shfl_xor(sn0, 1); sn0 += __shfl_xor(sn0, 2);
    sn1 += __shfl_xor(sn1, 1); sn1 += __shfl_xor(sn1, 2);
    if (tc == 0) {
      atomicAdd(out_norm + bh * DH_ + trow, sn0);
      atomicAdd(out_norm + bh * DH_ + trow + 64, sn1);
    }
    float* obh = out_kv + bh * DH_ * DH_;
#pragma unroll
    for (int mt = 0; mt < 4; mt++)
#pragma unroll
      for (int nt = 0; nt < 4; nt++) {
        int row = wr + mt * 16 + quad * 4;
        int col = wc + nt * 16 + l16;
#pragma unroll
        for (int r = 0; r < 4; r++)
          atomicAdd(obh + (size_t)(row + r) * DH_ + col, acc[mt][nt][r]);
      }
  }
}

extern "C" void kernel_launch(void* const* d_in, const int* in_sizes, int n_in,
                              void* d_out, int out_size, void* d_ws, size_t ws_size,
                              hipStream_t stream) {
  const float* x        = (const float*)d_in[0];
  const float* gamma    = (const float*)d_in[1];
  const float* w_qkv    = (const float*)d_in[2];
  const float* w_out    = (const float*)d_in[3];
  const float* hg       = (const float*)d_in[4];
  const float* mem_kv   = (const float*)d_in[5];
  const float* mem_norm = (const float*)d_in[6];
  float* out      = (float*)d_out;
  float* out_kv   = out + (size_t)B_ * N_ * D_;
  float* out_norm = out_kv + (size_t)B_ * H_ * DH_ * DH_;

  char* ws = (char*)d_ws;
  size_t off = 0;
  auto alloc = [&](size_t bytes) -> void* {
    void* p = ws + off;
    off += (bytes + 255) & ~(size_t)255;
    return p;
  };
  bf16*  xn   = (bf16*)alloc((size_t)B_ * N_ * D_ * 2);
  bf16*  wqb  = (bf16*)alloc((size_t)NO_ * D_ * 2);
  bf16*  wob  = (bf16*)alloc((size_t)D_ * D_ * 2);
  bf16*  qkvb = (bf16*)alloc((size_t)B_ * N_ * NO_ * 2);
  bf16*  qr   = (bf16*)alloc((size_t)B_ * H_ * N_ * DH_ * 2);
  bf16*  kr   = (bf16*)alloc((size_t)B_ * H_ * N_ * DH_ * 2);
  bf16*  vT   = (bf16*)alloc((size_t)B_ * H_ * DH_ * N_ * 2);
  bf16*  kfT  = (bf16*)alloc((size_t)B_ * H_ * DH_ * N_ * 2);  // written early (prep2)
  float* qden = (float*)alloc((size_t)B_ * H_ * N_ * 4);
  float* kden = (float*)alloc((size_t)B_ * H_ * N_ * 4);
  bf16*  attnb= (bf16*)alloc((size_t)B_ * H_ * N_ * DH_ * 2);
  bf16*  mkvT = (bf16*)alloc((size_t)B_ * H_ * DH_ * DH_ * 2);
  bf16*  pO    = (bf16*)alloc((size_t)1536 * 64 * DH_ * 2);
  float* pstat = (float*)alloc((size_t)1536 * 64 * 2 * 4);
  // Aliases (timeline-checked): comb reuses xn (dead after qkv-GEMM);
  // vnT reuses kr (dead after attn2; retrieve2 runs strictly after).
  bf16*  comb = xn;
  bf16*  vnT  = kr;
  (void)in_sizes; (void)n_in; (void)out_size; (void)ws_size;

  k_front<<<dim3(2 * B_ * N_ + B_ * H_), 256, 0, stream>>>(
      x, gamma, xn,
      (const float4*)w_qkv, (bf16x4*)wqb, NO_ * D_ / 4,
      (const float4*)w_out, (bf16x4*)wob, D_ * D_ / 4,
      mem_kv, mem_norm, mkvT, out_kv, out_norm);
  k_gemm_qkv<<<dim3(NO_ / 128, B_ * N_ / 128), 256, 0, stream>>>(xn, wqb, qkvb, NO_, D_);
  k_prep2<<<dim3(N_ / 64, H_, B_), 256, 0, stream>>>(qkvb, mem_norm, qr, kr, vT, kfT, qden, kden);
  k_attn2<<<dim3(1280), 256, 0, stream>>>(qr, kr, vT, attnb, pO, pstat);
  k_retrieve2<<<dim3(N_ / 64, H_, B_), 256, 0, stream>>>(qkvb, mkvT, qden, kden, attnb, pO, pstat, hg, comb, vnT);
  k_tail<<<dim3(512), 256, 0, stream>>>(comb, wob, out, kfT, vnT, out_kv, out_norm);
}